// Round 1
// 434.448 us; speedup vs baseline: 1.0053x; 1.0053x over previous
//
#include <hip/hip_runtime.h>
#include <stdint.h>

// Problem constants: B=32, T=4096, Dq=Dk=512, A=512
#define DQ 512
#define DK 512
#define NA 512
#define NBATCH 32
#define M_TOTAL (NBATCH * 4096)

#define BM 128
#define BK 32
#define KITERS (DK / BK)                 // 16
#define NBLK 256                         // persistent blocks, 1 per CU
#define ROUNDS (M_TOTAL / (BM * NBLK))   // 4 m-tiles per block
#define NT (ROUNDS * KITERS)             // 64 pipeline steps

typedef __attribute__((ext_vector_type(8))) short bf16x8;   // MFMA A/B frag (4 VGPRs)
typedef __attribute__((ext_vector_type(4))) float f32x4;    // MFMA C/D frag

// async global->LDS, 16B/lane. LDS dst = wave-uniform base + lane*16.
__device__ __forceinline__ void gll16(const void* g, void* l) {
  __builtin_amdgcn_global_load_lds(
      (const __attribute__((address_space(1))) uint32_t*)g,
      (__attribute__((address_space(3))) uint32_t*)l, 16, 0, 0);
}

// fp32 pair -> packed bf16 (round-half-up): 2 adds + v_perm_b32.
__device__ __forceinline__ uint32_t pack2bf16(float a, float b) {
  uint32_t ua = __float_as_uint(a) + 0x8000u;
  uint32_t ub = __float_as_uint(b) + 0x8000u;
  return __builtin_amdgcn_perm(ub, ua, 0x07060302);   // {ub.hi16 : ua.hi16}
}

// fast tanh: 1 - 2/(e^{2x}+1); correct limits at +/-inf
__device__ __forceinline__ float fast_tanh(float x) {
  float e = __expf(2.0f * x);
  return 1.0f - 2.0f * __builtin_amdgcn_rcpf(e + 1.0f);
}

// --- merged prep (W-transpose -> K-blocked tiled bf16) + qpb (exact fp32) ---
// Tiled layout: WkTt[(d>>5)*16384 + n*32 + (d&31)] = bf16(W[512+d][n])
// -> per K-iter the 32KB B panel is contiguous.
__global__ void prep_kernel(const float* __restrict__ W,
                            const float* __restrict__ q,
                            const float* __restrict__ bias,
                            uint16_t* __restrict__ WkTt,
                            float* __restrict__ qpb) {
  const int tid = threadIdx.x;
  if (blockIdx.x < 64) {
    __shared__ uint16_t T[64][65];
    const int d0 = (blockIdx.x & 7) * 64;
    const int a0 = (blockIdx.x >> 3) * 64;
#pragma unroll
    for (int j = 0; j < 16; ++j) {
      int dd = j * 4 + (tid >> 6);
      int aa = tid & 63;   // coalesced read
      uint32_t u = __float_as_uint(W[(size_t)(DQ + d0 + dd) * NA + a0 + aa]) + 0x8000u;
      T[dd][aa] = (uint16_t)(u >> 16);
    }
    __syncthreads();
#pragma unroll
    for (int j = 0; j < 8; ++j) {
      int aa = j * 8 + (tid >> 5);
      int n  = a0 + aa;
      int dp = (tid & 31) * 2;
      int d  = d0 + dp;
      uint32_t val = (uint32_t)T[dp][aa] | ((uint32_t)T[dp + 1][aa] << 16);
      *(uint32_t*)(WkTt + (size_t)(d >> 5) * 16384 + n * 32 + (d & 31)) = val;
    }
  } else {
    const int bb = blockIdx.x - 64;
    const int b  = bb >> 1;
    const int a  = (bb & 1) * 256 + tid;
    const float* qr = q + b * DQ;   // wave-uniform -> scalar loads
    float acc = bias[a];
#pragma unroll 8
    for (int d = 0; d < DQ; ++d)
      acc = fmaf(qr[d], W[(size_t)d * NA + a], acc);
    qpb[b * NA + a] = acc;
  }
}

// --- fused persistent-block GEMM (128x512 tile, bf16 MFMA) + tanh + v-dot ---
// Pipeline: triple-buffered B (global_load_lds, depth-2 prefetch), double-
// buffered A (reg float4 -> pack -> ds_write, depth-2), raw s_barrier with
// COUNTED s_waitcnt vmcnt(2): B-DMA never drains to 0 in the main loop (T3/T4).
// FIFO invariant at top of step t: [B(t):2, A(t+1):1, B(t+1):2] -> vmcnt(2)
// drains {B(t), A(t+1)}, leaves B(t+1) in flight. Issue order inside each
// step MUST be A-load first, then B-DMA. Extra epilogue loads/stores only
// append younger ops -> vmcnt(2) is still safe (over-drains, never under-).
__global__ __launch_bounds__(1024, 4)
void score_kernel(const float* __restrict__ Kmat,        // fp32 [M_TOTAL, DK]
                  const uint16_t* __restrict__ WkTt,     // tiled bf16 [16][512][32]
                  const float* __restrict__ qpb,         // fp32 [NBATCH, NA]
                  const float* __restrict__ v,           // fp32 [NA]
                  float* __restrict__ out) {             // fp32 [M_TOTAL]
  __shared__ __align__(16) uint16_t Bs[3 * NA * BK];     // 96 KB triple buffer
  __shared__ __align__(16) uint16_t As[2 * BM * BK];     // 16 KB double buffer
  __shared__ float part[8][BM];                          // 4 KB

  const int tid  = threadIdx.x;
  const int lane = tid & 63;
  const int w    = tid >> 6;       // 16 waves: 2 row-groups x 8 col-groups
  const int wc   = w & 7;          // col group -> cols wc*64 .. wc*64+63
  const int wr   = w >> 3;         // row group -> rows wr*64 .. wr*64+63
  const int r16  = lane & 15;
  const int quad = lane >> 4;
  const int sw   = quad ^ ((r16 >> 1) & 3);   // granule swizzle slot (2-way max = free)
  const int bid  = blockIdx.x;

  // ---- B-DMA lane constants: 2 granules (16 B) per thread per step ----
  const uint16_t* bconst0;
  const uint16_t* bconst1;
  {
    int s0 = tid;         int n0 = s0 >> 2, k0 = (s0 & 3) ^ ((n0 >> 1) & 3);
    int s1 = 1024 + tid;  int n1 = s1 >> 2, k1 = (s1 & 3) ^ ((n1 >> 1) & 3);
    bconst0 = WkTt + n0 * 32 + k0 * 8;   // inverse-swizzled global source
    bconst1 = WkTt + n1 * 32 + k1 * 8;
  }
  const int bdst0 = (0 * 1024 + w * 64) * 16;   // wave-uniform LDS byte base
  const int bdst1 = (1 * 1024 + w * 64) * 16;

  // ---- A staging: one float4 (4 k-elems of one row) per thread per step ----
  const int arow = tid >> 3;            // 0..127
  const int akp  = (tid & 7) * 4;
  const int As_off = arow * 64 + (((akp >> 3) ^ ((arow >> 1) & 3)) * 16) + (akp & 7) * 2;
  const float* ap = Kmat + (size_t)bid * BM * DK + (size_t)arow * DK + akp;

  // ---- fragment read byte offsets (swizzled) ----
  const int a_ro = (wr * 64 + r16) * 64 + sw * 16;   // + ms*1024
  const int b_ro = (wc * 64 + r16) * 64 + sw * 16;   // + ns*1024

  f32x4 acc[4][4];
#pragma unroll
  for (int i = 0; i < 4; ++i)
#pragma unroll
    for (int j = 0; j < 4; ++j) { f32x4 z = {0.f, 0.f, 0.f, 0.f}; acc[i][j] = z; }

  float vv[4];
#pragma unroll
  for (int ns = 0; ns < 4; ++ns) vv[ns] = v[wc * 64 + ns * 16 + r16];

  // ---- prologue: establish FIFO [B0:2, A1:1, B1:2] ----
  float4 c = *(const float4*)ap;   // A(0)
  ap += BK;
  gll16((const void*)bconst0, (void*)((char*)Bs + bdst0));            // B(0)
  gll16((const void*)bconst1, (void*)((char*)Bs + bdst1));
  asm volatile("s_waitcnt vmcnt(2)" ::: "memory");                    // A(0) done
  {
    uint2 p; p.x = pack2bf16(c.x, c.y); p.y = pack2bf16(c.z, c.w);
    *(uint2*)((char*)As + As_off) = p;                                // As[0]
  }
  c = *(const float4*)ap;          // A(1)
  ap += BK;
  gll16((const void*)(bconst0 + 16384), (void*)((char*)Bs + 32768 + bdst0));  // B(1)
  gll16((const void*)(bconst1 + 16384), (void*)((char*)Bs + 32768 + bdst1));

  int rdB = 0;   // t % 3
#pragma unroll 1
  for (int t = 0; t < NT; ++t) {
    // counted drain: B(t)+A(t+1) complete; B(t+1) stays in flight (never 0 mid-loop)
    if (t < NT - 1)
      asm volatile("s_waitcnt vmcnt(2) lgkmcnt(0)" ::: "memory");
    else
      asm volatile("s_waitcnt vmcnt(0) lgkmcnt(0)" ::: "memory");
    __builtin_amdgcn_s_barrier();

    if (t + 1 < NT) {   // pack A(t+1) -> As[(t+1)&1] (regs drained by vmcnt above)
      uint2 p; p.x = pack2bf16(c.x, c.y); p.y = pack2bf16(c.z, c.w);
      *(uint2*)((char*)As + ((t + 1) & 1) * 8192 + As_off) = p;
    }
    if (t + 2 < NT) {   // issue A(t+2) FIRST, then B(t+2) (FIFO discipline)
      c = *(const float4*)ap;
      ap += BK;
      if (((t + 3) & 15) == 0) ap += (size_t)NBLK * BM * DK - DK;   // next m-tile
      asm volatile("" ::: "memory");   // pin A-load ahead of B-DMA in vmcnt FIFO
      int wrB = rdB + 2; if (wrB >= 3) wrB -= 3;
      const int itn = (t + 2) & 15;    // B depends only on k-iter (same panel each tile)
      gll16((const void*)(bconst0 + itn * 16384), (void*)((char*)Bs + wrB * 32768 + bdst0));
      gll16((const void*)(bconst1 + itn * 16384), (void*)((char*)Bs + wrB * 32768 + bdst1));
    }

    // ---- frag reads (2-way max bank aliasing = free) + MFMA ----
    const char* Abase = (const char*)As + (t & 1) * 8192;
    const char* Bbase = (const char*)Bs + rdB * 32768;
    bf16x8 af[4], bfr[4];
#pragma unroll
    for (int ms = 0; ms < 4; ++ms) af[ms] = *(const bf16x8*)(Abase + a_ro + ms * 1024);
#pragma unroll
    for (int ns = 0; ns < 4; ++ns) bfr[ns] = *(const bf16x8*)(Bbase + b_ro + ns * 1024);
#pragma unroll
    for (int ms = 0; ms < 4; ++ms)
#pragma unroll
      for (int ns = 0; ns < 4; ++ns)
        acc[ms][ns] = __builtin_amdgcn_mfma_f32_16x16x32_bf16(
            af[ms], bfr[ns], acc[ms][ns], 0, 0, 0);

    // ---- per-tile epilogue: tanh(acc + qpb) * v, reduce 512 cols -> 128 rows ----
    if ((t & 15) == 15) {
      const int tile  = bid + (t >> 4) * NBLK;
      const int b_idx = tile >> 5;          // 32 tiles per batch
      float qv[4];
#pragma unroll
      for (int ns = 0; ns < 4; ++ns) qv[ns] = qpb[b_idx * NA + wc * 64 + ns * 16 + r16];
#pragma unroll
      for (int ms = 0; ms < 4; ++ms) {
#pragma unroll
        for (int reg = 0; reg < 4; ++reg) {
          float s = 0.f;
#pragma unroll
          for (int ns = 0; ns < 4; ++ns) {
            float x = acc[ms][ns][reg] + qv[ns];
            s = fmaf(fast_tanh(x), vv[ns], s);
          }
          // C/D row = quad*4+reg; its 16 cols live in this quad's lanes
          s += __shfl_xor(s, 1);
          s += __shfl_xor(s, 2);
          s += __shfl_xor(s, 4);
          s += __shfl_xor(s, 8);
          if (r16 == 0) part[wc][wr * 64 + ms * 16 + quad * 4 + reg] = s;
        }
      }
      asm volatile("s_waitcnt lgkmcnt(0)" ::: "memory");   // lgkm only: B-DMA stays in flight
      __builtin_amdgcn_s_barrier();
      if (tid < BM) {
        float s = 0.f;
#pragma unroll
        for (int cg = 0; cg < 8; ++cg) s += part[cg][tid];
        out[(size_t)tile * BM + tid] = s;
      }
#pragma unroll
      for (int i = 0; i < 4; ++i)
#pragma unroll
        for (int j = 0; j < 4; ++j) { f32x4 z = {0.f, 0.f, 0.f, 0.f}; acc[i][j] = z; }
    }
    rdB += 1; if (rdB == 3) rdB = 0;
  }
}

extern "C" void kernel_launch(void* const* d_in, const int* in_sizes, int n_in,
                              void* d_out, int out_size, void* d_ws, size_t ws_size,
                              hipStream_t stream) {
  const float* q = (const float*)d_in[0];
  const float* k = (const float*)d_in[1];
  const float* W = (const float*)d_in[2];
  const float* b = (const float*)d_in[3];
  const float* v = (const float*)d_in[4];
  float* out = (float*)d_out;

  // ws: [0,64KB) qpb fp32; [64KB,576KB) WkTt bf16 (tiled)
  float* qpb = (float*)d_ws;
  uint16_t* WkTt = (uint16_t*)((char*)d_ws + 65536);

  prep_kernel<<<128, 256, 0, stream>>>(W, q, b, WkTt, qpb);
  score_kernel<<<NBLK, 1024, 0, stream>>>(k, WkTt, qpb, v, out);
}